// Round 10
// baseline (374.735 us; speedup 1.0000x reference)
//
#include <hip/hip_runtime.h>
#include <hip/hip_bf16.h>
#include <math.h>

// Problem constants (reference: B=64, L=1024, H=64, VOCAB=64)
#define BB 64
#define LL 1024
#define HH 64

typedef float v4f __attribute__((ext_vector_type(4)));
#define F4 __builtin_elementwise_fma

// ---------------------------------------------------------------------------
// Kernel 1: per-token phase, v2 — J=2 register blocking to halve LDS ops.
// block = 256 threads, 32 tokens/block, grid = 2048.
// Every fp accumulation keeps the ORIGINAL 4-partial structure and fold
// order, so all outputs are bit-identical to the v1 kernel:
//   B : FF1 (64->128, ReLU). thread = (jj, tg): cols {jj, jj+64}, 8 tokens.
//   C : FF2 (128->64) + residual -> x into hn_s scratch (no LN yet).
//       thread = (ii, tg): cols {ii, ii+32}, 4 tokens.
//   C2: LayerNorm in place on hn_s (original lane mapping, shfl reduce).
//   D : k/v projections -> kv staging in t1_s (dead after C).
//   D2: norms + global knv/vthr writes, q for t==1023 (original mapping).
// ---------------------------------------------------------------------------
__global__ __launch_bounds__(256, 1)
void token_kernel(const int* __restrict__ seq,
                  const float* __restrict__ embed_W,
                  const float* __restrict__ ff_W1, const float* __restrict__ ff_b1,
                  const float* __restrict__ ff_W2, const float* __restrict__ ff_b2,
                  const float* __restrict__ ln_g, const float* __restrict__ ln_b,
                  const float* __restrict__ kp_W, const float* __restrict__ vp_W,
                  const float* __restrict__ qp_W,
                  float* __restrict__ knv, float* __restrict__ vthr,
                  float* __restrict__ qbuf)
{
    __shared__ __align__(16) float h_s[32][64];    // 8 KB
    __shared__ __align__(16) float t1_s[32][128];  // 16 KB (FF1 out; kv staging in D)
    __shared__ __align__(16) float hn_s[32][64];   // 8 KB  (x scratch -> hn)

    const int tid  = threadIdx.x;
    const int tok0 = blockIdx.x * 32;

    // ---- Stage A: embedding gather into LDS ----
#pragma unroll
    for (int k = 0; k < 8; ++k) {
        int e   = k * 256 + tid;
        int tok = e >> 6, i = e & 63;
        int s   = seq[tok0 + tok];
        h_s[tok][i] = embed_W[s * 64 + i];
    }
    __syncthreads();

    // ---- Stage B: FF1 (64 -> 128, ReLU), J=2 x T=8 ----
    {
        const int jj = tid & 63;
        const int tg = tid >> 6;                   // 4 groups x 8 tokens
        float a[2][8][4];
        const float b10 = ff_b1[jj];
        const float b11 = ff_b1[jj + 64];
#pragma unroll
        for (int t = 0; t < 8; ++t) {
            a[0][t][0] = b10; a[0][t][1] = 0.f; a[0][t][2] = 0.f; a[0][t][3] = 0.f;
            a[1][t][0] = b11; a[1][t][1] = 0.f; a[1][t][2] = 0.f; a[1][t][3] = 0.f;
        }
#pragma unroll
        for (int cc = 0; cc < 16; ++cc) {
            float w0[4], w1[4];
#pragma unroll
            for (int r = 0; r < 4; ++r) {
                w0[r] = ff_W1[(4*cc + r) * 128 + jj];
                w1[r] = ff_W1[(4*cc + r) * 128 + jj + 64];
            }
#pragma unroll
            for (int t = 0; t < 8; ++t) {
                const float4 hv = ((const float4*)h_s[tg * 8 + t])[cc];
                a[0][t][0] = fmaf(hv.x, w0[0], a[0][t][0]);
                a[0][t][1] = fmaf(hv.y, w0[1], a[0][t][1]);
                a[0][t][2] = fmaf(hv.z, w0[2], a[0][t][2]);
                a[0][t][3] = fmaf(hv.w, w0[3], a[0][t][3]);
                a[1][t][0] = fmaf(hv.x, w1[0], a[1][t][0]);
                a[1][t][1] = fmaf(hv.y, w1[1], a[1][t][1]);
                a[1][t][2] = fmaf(hv.z, w1[2], a[1][t][2]);
                a[1][t][3] = fmaf(hv.w, w1[3], a[1][t][3]);
            }
        }
#pragma unroll
        for (int t = 0; t < 8; ++t) {
            const int tok = tg * 8 + t;
            t1_s[tok][jj]      = fmaxf((a[0][t][0] + a[0][t][1])
                                     + (a[0][t][2] + a[0][t][3]), 0.f);
            t1_s[tok][jj + 64] = fmaxf((a[1][t][0] + a[1][t][1])
                                     + (a[1][t][2] + a[1][t][3]), 0.f);
        }
    }
    __syncthreads();

    // ---- Stage C: FF2 (128 -> 64) + residual -> x into hn_s, J=2 x T=4 ----
    {
        const int ii = tid & 31;
        const int tg = tid >> 5;                   // 8 groups x 4 tokens
        const int i0 = ii, i1 = ii + 32;
        float accf[2][4];
        const float b20 = ff_b2[i0], b21 = ff_b2[i1];
#pragma unroll
        for (int t = 0; t < 4; ++t) { accf[0][t] = b20; accf[1][t] = b21; }
#pragma unroll
        for (int h = 0; h < 2; ++h) {
            float a[2][4][4];
#pragma unroll
            for (int t = 0; t < 4; ++t)
#pragma unroll
                for (int r = 0; r < 4; ++r) { a[0][t][r] = 0.f; a[1][t][r] = 0.f; }
#pragma unroll
            for (int cc = 0; cc < 16; ++cc) {
                float w0[4], w1[4];
#pragma unroll
                for (int r = 0; r < 4; ++r) {
                    w0[r] = ff_W2[(h*64 + 4*cc + r) * 64 + i0];
                    w1[r] = ff_W2[(h*64 + 4*cc + r) * 64 + i1];
                }
#pragma unroll
                for (int t = 0; t < 4; ++t) {
                    const float4 tv = ((const float4*)&t1_s[tg * 4 + t][h * 64])[cc];
                    a[0][t][0] = fmaf(tv.x, w0[0], a[0][t][0]);
                    a[0][t][1] = fmaf(tv.y, w0[1], a[0][t][1]);
                    a[0][t][2] = fmaf(tv.z, w0[2], a[0][t][2]);
                    a[0][t][3] = fmaf(tv.w, w0[3], a[0][t][3]);
                    a[1][t][0] = fmaf(tv.x, w1[0], a[1][t][0]);
                    a[1][t][1] = fmaf(tv.y, w1[1], a[1][t][1]);
                    a[1][t][2] = fmaf(tv.z, w1[2], a[1][t][2]);
                    a[1][t][3] = fmaf(tv.w, w1[3], a[1][t][3]);
                }
            }
#pragma unroll
            for (int t = 0; t < 4; ++t) {
                accf[0][t] += (a[0][t][0] + a[0][t][1]) + (a[0][t][2] + a[0][t][3]);
                accf[1][t] += (a[1][t][0] + a[1][t][1]) + (a[1][t][2] + a[1][t][3]);
            }
        }
#pragma unroll
        for (int t = 0; t < 4; ++t) {
            const int tok = tg * 4 + t;
            hn_s[tok][i0] = h_s[tok][i0] + accf[0][t];   // x, pre-LN
            hn_s[tok][i1] = h_s[tok][i1] + accf[1][t];
        }
    }
    __syncthreads();

    // ---- Stage C2: LayerNorm in place (original mapping; shfl reduce) ----
    {
        const int i  = tid & 63;
        const int w4 = tid >> 6;
        const float gi = ln_g[i];
        const float bi = ln_b[i];
#pragma unroll
        for (int tk = 0; tk < 8; ++tk) {
            const int tok = w4 * 8 + tk;
            float x = hn_s[tok][i];
            float s = x;
#pragma unroll
            for (int m = 32; m > 0; m >>= 1) s += __shfl_xor(s, m);
            float mu = s * (1.f / 64.f);
            float d  = x - mu;
            float s2 = d * d;
#pragma unroll
            for (int m = 32; m > 0; m >>= 1) s2 += __shfl_xor(s2, m);
            float var = s2 * (1.f / 64.f);
            hn_s[tok][i] = d / sqrtf(var + 1e-5f) * gi + bi;
        }
    }
    __syncthreads();

    // ---- Stage D: k/v projections into t1_s staging, J=2 x T=4 ----
    // t1_s layout reuse: [tok][0..63] = ka, [tok][64..127] = va
    {
        const int ii = tid & 31;
        const int tg = tid >> 5;                   // 8 groups x 4 tokens
        const int i0 = ii, i1 = ii + 32;
        float ak[2][4][4], av[2][4][4];
#pragma unroll
        for (int t = 0; t < 4; ++t)
#pragma unroll
            for (int r = 0; r < 4; ++r) {
                ak[0][t][r] = 0.f; ak[1][t][r] = 0.f;
                av[0][t][r] = 0.f; av[1][t][r] = 0.f;
            }
#pragma unroll
        for (int cc = 0; cc < 16; ++cc) {
            float wk0[4], wk1[4], wv0[4], wv1[4];
#pragma unroll
            for (int r = 0; r < 4; ++r) {
                wk0[r] = kp_W[(4*cc + r) * 64 + i0];
                wk1[r] = kp_W[(4*cc + r) * 64 + i1];
                wv0[r] = vp_W[(4*cc + r) * 64 + i0];
                wv1[r] = vp_W[(4*cc + r) * 64 + i1];
            }
#pragma unroll
            for (int t = 0; t < 4; ++t) {
                const float4 hv = ((const float4*)hn_s[tg * 4 + t])[cc];
                ak[0][t][0] = fmaf(hv.x, wk0[0], ak[0][t][0]);
                ak[0][t][1] = fmaf(hv.y, wk0[1], ak[0][t][1]);
                ak[0][t][2] = fmaf(hv.z, wk0[2], ak[0][t][2]);
                ak[0][t][3] = fmaf(hv.w, wk0[3], ak[0][t][3]);
                ak[1][t][0] = fmaf(hv.x, wk1[0], ak[1][t][0]);
                ak[1][t][1] = fmaf(hv.y, wk1[1], ak[1][t][1]);
                ak[1][t][2] = fmaf(hv.z, wk1[2], ak[1][t][2]);
                ak[1][t][3] = fmaf(hv.w, wk1[3], ak[1][t][3]);
                av[0][t][0] = fmaf(hv.x, wv0[0], av[0][t][0]);
                av[0][t][1] = fmaf(hv.y, wv0[1], av[0][t][1]);
                av[0][t][2] = fmaf(hv.z, wv0[2], av[0][t][2]);
                av[0][t][3] = fmaf(hv.w, wv0[3], av[0][t][3]);
                av[1][t][0] = fmaf(hv.x, wv1[0], av[1][t][0]);
                av[1][t][1] = fmaf(hv.y, wv1[1], av[1][t][1]);
                av[1][t][2] = fmaf(hv.z, wv1[2], av[1][t][2]);
                av[1][t][3] = fmaf(hv.w, wv1[3], av[1][t][3]);
            }
        }
#pragma unroll
        for (int t = 0; t < 4; ++t) {
            const int tok = tg * 4 + t;
            t1_s[tok][i0]      = (ak[0][t][0] + ak[0][t][1]) + (ak[0][t][2] + ak[0][t][3]);
            t1_s[tok][i1]      = (ak[1][t][0] + ak[1][t][1]) + (ak[1][t][2] + ak[1][t][3]);
            t1_s[tok][64 + i0] = (av[0][t][0] + av[0][t][1]) + (av[0][t][2] + av[0][t][3]);
            t1_s[tok][64 + i1] = (av[1][t][0] + av[1][t][1]) + (av[1][t][2] + av[1][t][3]);
        }
    }
    __syncthreads();

    // ---- Stage D2: norms + global writes (original mapping), q for t==1023 ----
    {
        const int i  = tid & 63;
        const int w4 = tid >> 6;
#pragma unroll
        for (int tk = 0; tk < 8; ++tk) {
            const int tok = w4 * 8 + tk;
            const int tg_ = tok0 + tok;
            const int b   = tg_ >> 10;
            const int t   = tg_ & 1023;
            if (t < 1023) {
                float ka = t1_s[tok][i];
                float va = t1_s[tok][64 + i];
                float kn2 = ka * ka, vn2 = va * va;
#pragma unroll
                for (int m = 32; m > 0; m >>= 1) {
                    kn2 += __shfl_xor(kn2, m);
                    vn2 += __shfl_xor(vn2, m);
                }
                float knorm = fmaxf(sqrtf(kn2), 1e-12f);
                size_t row = ((size_t)b * 1024 + t) * 128;
                knv[row + i]      = ka / knorm;
                knv[row + 64 + i] = va;
                if (i == 0) vthr[b * 1024 + t] = 0.16f * vn2;   // SQUARED threshold
            } else {
                const float4* hn4 = (const float4*)hn_s[tok];
                float qa0=0.f,qa1=0.f,qa2=0.f,qa3=0.f;
#pragma unroll
                for (int w = 0; w < 16; ++w) {
                    float4 hv = hn4[w];
                    qa0 = fmaf(hv.x, qp_W[(4*w+0)*64 + i], qa0);
                    qa1 = fmaf(hv.y, qp_W[(4*w+1)*64 + i], qa1);
                    qa2 = fmaf(hv.z, qp_W[(4*w+2)*64 + i], qa2);
                    qa3 = fmaf(hv.w, qp_W[(4*w+3)*64 + i], qa3);
                }
                qbuf[b * 64 + i] = (qa0 + qa1) + (qa2 + qa3);
            }
        }
    }
}

// ---------------------------------------------------------------------------
// Kernel 2: sequential fast-weight scan + output head.
// ROUND-8 VERBATIM: G=2 chunks, 4-wave column split (best measured, 211 µs).
// ---------------------------------------------------------------------------

template<int CTRL>
__device__ __forceinline__ float dppadd(float x) {
    int y = __builtin_amdgcn_update_dpp(0, __float_as_int(x), CTRL, 0xF, 0xF, true);
    return x + __int_as_float(y);
}

__device__ __forceinline__ float bcast63(float x) {
    return __int_as_float(__builtin_amdgcn_readlane(__float_as_int(x), 63));
}

// full-wave (64 lane) sum, result broadcast (prologue use)
__device__ __forceinline__ float wave_sum64(float x) {
    x = dppadd<0x111>(x); x = dppadd<0x112>(x);
    x = dppadd<0x114>(x); x = dppadd<0x118>(x);
    x = dppadd<0x142>(x); x = dppadd<0x143>(x);
    return bcast63(x);
}

// four independent wave sums, DPP levels interleaved (latency amortized)
__device__ __forceinline__ void wsum4(float& a, float& b, float& c, float& d) {
    a = dppadd<0x111>(a); b = dppadd<0x111>(b); c = dppadd<0x111>(c); d = dppadd<0x111>(d);
    a = dppadd<0x112>(a); b = dppadd<0x112>(b); c = dppadd<0x112>(c); d = dppadd<0x112>(d);
    a = dppadd<0x114>(a); b = dppadd<0x114>(b); c = dppadd<0x114>(c); d = dppadd<0x114>(d);
    a = dppadd<0x118>(a); b = dppadd<0x118>(b); c = dppadd<0x118>(c); d = dppadd<0x118>(d);
    a = dppadd<0x142>(a); b = dppadd<0x142>(b); c = dppadd<0x142>(c); d = dppadd<0x142>(d);
    a = dppadd<0x143>(a); b = dppadd<0x143>(b); c = dppadd<0x143>(c); d = dppadd<0x143>(d);
    a = bcast63(a); b = bcast63(b); c = bcast63(c); d = bcast63(d);
}

// load this wave's quarter of a kn row into quarter-set P (4 x ds_read_b128)
#define LOADK4(P, ROW) do { \
    const float* r_ = (ROW) + (wid << 4); \
    P##0 = *(const v4f*)(r_ + 0);  P##1 = *(const v4f*)(r_ + 4); \
    P##2 = *(const v4f*)(r_ + 8);  P##3 = *(const v4f*)(r_ + 12); \
} while (0)

// M(quarter) += G * P(quarter)   (branchless; G==0 exact no-op on finite P)
#define UPD4(P, G) do { \
    v4f gv_ = {G, G, G, G}; \
    m0 = F4(gv_, P##0, m0); m1 = F4(gv_, P##1, m1); \
    m2 = F4(gv_, P##2, m2); m3 = F4(gv_, P##3, m3); \
} while (0)

// One chunk u (steps 2u, 2u+1).
#define CHUNK2(UP, UQ, XR, XS, ROW2, ROW3, TH2P, TH3P, PAR) do { \
    UPD4(UP, gdp); \
    UPD4(UQ, gdq); \
    v4f q_ = F4(m0, XR##0, F4(m1, XR##1, F4(m2, XR##2, m3 * XR##3))); \
    float own0_ = (q_.x + q_.y) + (q_.z + q_.w); \
    v4f r_ = F4(m0, XS##0, F4(m1, XS##1, F4(m2, XS##2, m3 * XS##3))); \
    float own1_ = (r_.x + r_.y) + (r_.z + r_.w); \
    ((float2*)pex[PAR][wid])[lane] = make_float2(own0_, own1_); \
    asm volatile("s_waitcnt lgkmcnt(0)\n\ts_barrier" ::: "memory"); \
    float2 p0_ = ((const float2*)pex[PAR][0])[lane]; \
    float2 p1_ = ((const float2*)pex[PAR][1])[lane]; \
    float2 p2_ = ((const float2*)pex[PAR][2])[lane]; \
    float2 p3_ = ((const float2*)pex[PAR][3])[lane]; \
    float knl2_ = (ROW2)[lane]; \
    float knl3_ = (ROW3)[lane]; \
    float vv2_  = (ROW2)[64 + lane]; \
    float vv3_  = (ROW3)[64 + lane]; \
    float th2_  = *(TH2P); \
    float th3_  = *(TH3P); \
    LOADK4(UP, ROW2); \
    LOADK4(UQ, ROW3); \
    float base0_ = (p0_.x + p1_.x) + (p2_.x + p3_.x); \
    float base1_ = (p0_.y + p1_.y) + (p2_.y + p3_.y); \
    float d00_ = vv0 - base0_; \
    float d01_ = vv1 - base1_; \
    float x0_ = d00_ * d00_, x1_ = d00_ * d01_; \
    float x2_ = d01_ * d01_, x3_ = knl2_ * knl3_; \
    wsum4(x0_, x1_, x2_, x3_); \
    bool g0_ = x0_ > th0; \
    float corr_ = fmaf(2.f * c3, x1_, -(c3 * c3) * x0_); \
    float e1_ = g0_ ? (x2_ - corr_) : x2_; \
    bool g1_ = e1_ > th1; \
    float gd0_ = g0_ ? d00_ : 0.f; \
    float d1_  = fmaf(-c3, gd0_, d01_); \
    gdp = gd0_; \
    gdq = g1_ ? d1_ : 0.f; \
    vv0 = vv2_; vv1 = vv3_; th0 = th2_; th1 = th3_; c3 = x3_; \
} while (0)

// 8 chunks covering one 16-row buffer (steps 16c .. 16c+15).
#define BUF8(CB, NB, TP) \
    CHUNK2(U,V,S,T,(CB)+2*128, (CB)+3*128, (TP)+2, (TP)+3, 0); \
    CHUNK2(S,T,U,V,(CB)+4*128, (CB)+5*128, (TP)+4, (TP)+5, 1); \
    CHUNK2(U,V,S,T,(CB)+6*128, (CB)+7*128, (TP)+6, (TP)+7, 0); \
    CHUNK2(S,T,U,V,(CB)+8*128, (CB)+9*128, (TP)+8, (TP)+9, 1); \
    CHUNK2(U,V,S,T,(CB)+10*128,(CB)+11*128,(TP)+10,(TP)+11,0); \
    CHUNK2(S,T,U,V,(CB)+12*128,(CB)+13*128,(TP)+12,(TP)+13,1); \
    CHUNK2(U,V,S,T,(CB)+14*128,(CB)+15*128,(TP)+14,(TP)+15,0); \
    CHUNK2(S,T,U,V,(NB)+0*128, (NB)+1*128, (TP)+16,(TP)+17,1);

// async copy: 1024 B contiguous global -> contiguous LDS (one inst)
__device__ __forceinline__ void gl2lds_1k(const float* g, float* l, int lane) {
    __builtin_amdgcn_global_load_lds(
        (const __attribute__((address_space(1))) void*)(g + lane * 4),
        (__attribute__((address_space(3))) void*)l, 16, 0, 0);
}

// wave w stages rows 4w..4w+3 of a 16-row buffer (2 KB = 2 insts)
__device__ __forceinline__ void prefetch_quarter(const float* g, float* l,
                                                 int lane, int wid) {
#pragma unroll
    for (int j = 0; j < 2; ++j)
        gl2lds_1k(g + wid * 512 + j * 256, l + wid * 512 + j * 256, lane);
}

__global__ __launch_bounds__(256, 1)
void scan_kernel(const float* __restrict__ knv,
                 const float* __restrict__ vthr,
                 const float* __restrict__ qbuf,
                 const float* __restrict__ rp_W, const float* __restrict__ rp_b,
                 const float* __restrict__ out_W, const float* __restrict__ out_b,
                 float* __restrict__ out)
{
    const int b    = blockIdx.x;
    const int tid  = threadIdx.x;
    const int lane = tid & 63;
    const int wid  = tid >> 6;
    const float* knvb = knv  + (size_t)b * 1024 * 128;
    const float* thrb = vthr + (size_t)b * 1024;

    __shared__ __align__(16) float thr_s[1040];      // th^2 per step
    __shared__ __align__(16) float buf[3 * 2048];    // 3 x 8 KB buffers
    __shared__ __align__(16) float pex[2][4][128];   // [parity][wave][lane*2]
    __shared__ float sh[64];

    // M quarter: columns [16*wid, 16*wid+16) of lane's row (4 v4f)
    v4f m0={0,0,0,0}, m1={0,0,0,0}, m2={0,0,0,0}, m3={0,0,0,0};
    // four kn quarter-sets; roles alternate per chunk parity
    v4f S0,S1,S2,S3;
    v4f T0,T1,T2,T3;
    v4f U0,U1,U2,U3;
    v4f V0,V1,V2,V3;

    // staging: wave 0 also loads thr (4 insts); each wave 2 insts/buffer
    if (wid == 0) {
#pragma unroll
        for (int w = 0; w < 4; ++w) gl2lds_1k(thrb + w * 256, thr_s + w * 256, lane);
    }
    prefetch_quarter(knvb,        buf,        lane, wid);
    prefetch_quarter(knvb + 2048, buf + 2048, lane, wid);
    prefetch_quarter(knvb + 4096, buf + 4096, lane, wid);

    // zero pex: 1024 floats / 256 threads = 1 float4 each
    {
        float4 z4 = make_float4(0.f, 0.f, 0.f, 0.f);
        ((float4*)pex)[tid] = z4;
    }

    // thr + buffers 0,1 resident own-wave (buffer 2 = 2 insts in flight);
    // barrier makes all waves' quarters visible.
    asm volatile("s_waitcnt vmcnt(2) lgkmcnt(0)\n\ts_barrier" ::: "memory");

    // prologue: chunk 0 expects S=kn_0, T=kn_1, U=V = kn_{-2,-1} = 0
    LOADK4(S, buf);
    LOADK4(T, buf + 128);
    {
        v4f z_ = {0.f, 0.f, 0.f, 0.f};
        U0=z_;U1=z_;U2=z_;U3=z_;
        V0=z_;V1=z_;V2=z_;V3=z_;
    }
    float vv0 = buf[64 + lane];          // v_0[lane]
    float vv1 = buf[192 + lane];         // v_1[lane]
    float th0 = thr_s[0];
    float th1 = thr_s[1];
    float c3  = wave_sum64(buf[lane] * buf[128 + lane]);   // kn_0 . kn_1
    float gdp = 0.f, gdq = 0.f;

#pragma unroll 1
    for (int c = 0; c < 62; ++c) {
        // own outstanding <= 4 (buffers c+1, c+2); vmcnt(2) -> buffer c+1
        // resident own-wave; chunk barriers give cross-wave visibility.
        asm volatile("s_waitcnt vmcnt(2)" ::: "memory");
        const float* cb = buf + (c % 3) * 2048;
        const float* nb = buf + ((c + 1) % 3) * 2048;
        const float* tp = thr_s + c * 16;
        BUF8(cb, nb, tp)
        if (c <= 60)
            prefetch_quarter(knvb + (size_t)(c + 3) * 2048,
                             buf + (c % 3) * 2048, lane, wid);
    }
    asm volatile("s_waitcnt vmcnt(0)" ::: "memory");
    asm volatile("s_barrier" ::: "memory");   // all waves' buffers 62,63 staged
    {   // buffer 62 (slot 2), lookahead into buffer 63 (slot 0)
        const float* cb = buf + 2 * 2048;
        const float* nb = buf;
        const float* tp = thr_s + 62 * 16;
        BUF8(cb, nb, tp)
    }
    {   // buffer 63 (slot 0): steps 1008..1023 (1023 = dummy); NB dummy slot 1
        const float* cb = buf;
        const float* nb = buf + 2048;
        const float* tp = thr_s + 63 * 16;
        BUF8(cb, nb, tp)
    }
    // final update: M_{1022} = M_{1021} + gd_{1022} kn_{1022}^T
    // (gdp = gd_{1022}; U holds kn_{1022}: DOT source of the last chunk)
    UPD4(U, gdp);

    // ---- output head: vq = M q (quarter + exchange), wave 0 finishes ----
    {
        const v4f* qq = (const v4f*)(qbuf + b * 64);
        const int w4i = 4 * wid;
        v4f aq = F4(m0, qq[w4i+0], F4(m1, qq[w4i+1],
                 F4(m2, qq[w4i+2],  m3 * qq[w4i+3])));
        float vq_own = (aq.x + aq.y) + (aq.z + aq.w);
        pex[0][wid][lane] = vq_own;
        asm volatile("s_waitcnt lgkmcnt(0)\n\ts_barrier" ::: "memory");

        if (wid == 0) {
            float vq = (pex[0][0][lane] + pex[0][1][lane])
                     + (pex[0][2][lane] + pex[0][3][lane]);
            sh[lane] = vq;
            asm volatile("s_waitcnt lgkmcnt(0)" ::: "memory");
            float r = rp_b[lane];
#pragma unroll
            for (int ii = 0; ii < 64; ++ii) r = fmaf(sh[ii], rp_W[ii * 64 + lane], r);
            asm volatile("s_waitcnt lgkmcnt(0)" ::: "memory");
            sh[lane] = r;
            asm volatile("s_waitcnt lgkmcnt(0)" ::: "memory");
            float o = out_b[lane];
#pragma unroll
            for (int ii = 0; ii < 64; ++ii) o = fmaf(sh[ii], out_W[ii * 64 + lane], o);
            out[b * 64 + lane] = o;
        }
    }
}

// ---------------------------------------------------------------------------
// Launch. Workspace (fp32): knv[64][1024][128] (33.55 MB, t=1023 row unused) |
// vthr[64][1024] (262 KB) | qbuf[64][64]. Total ~33.9 MB.
// ---------------------------------------------------------------------------
extern "C" void kernel_launch(void* const* d_in, const int* in_sizes, int n_in,
                              void* d_out, int out_size, void* d_ws, size_t ws_size,
                              hipStream_t stream)
{
    const int*   seq   = (const int*)  d_in[0];
    const float* embed = (const float*)d_in[1];
    const float* ffW1  = (const float*)d_in[2];
    const float* ffb1  = (const float*)d_in[3];
    const float* ffW2  = (const float*)d_in[4];
    const float* ffb2  = (const float*)d_in[5];
    const float* lng   = (const float*)d_in[6];
    const float* lnb   = (const float*)d_in[7];
    const float* kpW   = (const float*)d_in[8];
    const float* vpW   = (const float*)d_in[9];
    const float* qpW   = (const float*)d_in[10];
    const float* rpW   = (const float*)d_in[11];
    const float* rpb   = (const float*)d_in[12];
    const float* outW  = (const float*)d_in[13];
    const float* outb  = (const float*)d_in[14];
    float* out = (float*)d_out;

    float* knv  = (float*)d_ws;
    float* vthr = knv  + (size_t)64 * 1024 * 128;
    float* qbuf = vthr + (size_t)64 * 1024;

    token_kernel<<<2048, 256, 0, stream>>>(seq, embed, ffW1, ffb1, ffW2, ffb2,
                                           lng, lnb, kpW, vpW, qpW,
                                           knv, vthr, qbuf);
    scan_kernel<<<64, 256, 0, stream>>>(knv, vthr, qbuf,
                                        rpW, rpb, outW, outb, out);
}